// Round 1
// baseline (177.415 us; speedup 1.0000x reference)
//
#include <hip/hip_runtime.h>
#include <hip/hip_bf16.h>

#define N0 300000
#define N1 60000
#define N2 6000
#define E1 1200000
#define E2 300000
#define D 128
#define DO 64

typedef __attribute__((ext_vector_type(8))) short bfrag8;
typedef __attribute__((ext_vector_type(4))) float f32x4;

#define WL_CAP 32768

// ---- layer 1: h init (history gather or self-loop+bias for uncached) ----
__global__ void k_init_h(const float* __restrict__ x,
                         const int* __restrict__ hmap,
                         const float* __restrict__ hist,
                         const float* __restrict__ Wself1,
                         const float* __restrict__ b1,
                         float* __restrict__ h) {
    int idx = blockIdx.x * blockDim.x + threadIdx.x;   // over N1*32 float4s
    if (idx >= N1 * 32) return;
    int node = idx >> 5, q = idx & 31;
    int m = hmap[node];
    float4* hv = (float4*)h;
    if (m >= 0) {
        hv[idx] = ((const float4*)hist)[m * 32 + q];
    } else {
        float acc[4];
#pragma unroll
        for (int j = 0; j < 4; j++) acc[j] = b1[q * 4 + j];
        for (int k = 0; k < D; k++) {
            float xv = x[node * D + k];
#pragma unroll
            for (int j = 0; j < 4; j++) acc[j] += xv * Wself1[k * D + q * 4 + j];
        }
        float4 o; o.x = acc[0]; o.y = acc[1]; o.z = acc[2]; o.w = acc[3];
        hv[idx] = o;
    }
}

// ---- find edges whose dst has no history (rare) ----
__global__ void k_scan(const int* __restrict__ dst1, const int* __restrict__ hmap,
                       int* __restrict__ cnt, int* __restrict__ list) {
    int e = blockIdx.x * blockDim.x + threadIdx.x;
    if (e >= E1) return;
    if (hmap[dst1[e]] < 0) {
        int i = atomicAdd(cnt, 1);
        if (i < WL_CAP) list[i] = e;
    }
}

// ---- process worklist edges: msg = W1[et]^T x[src], atomic add into h[dst] ----
__global__ void k_wl(const float* __restrict__ x, const int* __restrict__ src1,
                     const int* __restrict__ dst1, const int* __restrict__ et1,
                     const float* __restrict__ W1, const int* __restrict__ cnt,
                     const int* __restrict__ list, float* __restrict__ h) {
    int c = threadIdx.x;  // 128
    int n = *cnt; if (n > WL_CAP) n = WL_CAP;
    for (int i = blockIdx.x; i < n; i += gridDim.x) {
        int e = list[i];
        int s = src1[e], d = dst1[e], t = et1[e];
        float acc = 0.f;
        for (int k = 0; k < D; k++) acc += x[s * D + k] * W1[(t * D + k) * D + c];
        atomicAdd(&h[d * D + c], acc);
    }
}

// ---- BN batch stats ----
__global__ void k_stats(const float* __restrict__ h, float* __restrict__ stats) {
    __shared__ float s1[256], s2[256];
    int c = threadIdx.x & 127, sub = threadIdx.x >> 7;
    float a1 = 0.f, a2 = 0.f;
    for (int r = blockIdx.x * 2 + sub; r < N1; r += gridDim.x * 2) {
        float v = h[r * D + c];
        a1 += v; a2 += v * v;
    }
    s1[threadIdx.x] = a1; s2[threadIdx.x] = a2;
    __syncthreads();
    if (threadIdx.x < 128) {
        atomicAdd(&stats[c],       s1[threadIdx.x] + s1[threadIdx.x + 128]);
        atomicAdd(&stats[128 + c], s2[threadIdx.x] + s2[threadIdx.x + 128]);
    }
}

__global__ void k_params(const float* __restrict__ stats, const float* __restrict__ gamma,
                         const float* __restrict__ beta, float* __restrict__ params) {
    int c = threadIdx.x;  // 128
    float mean = stats[c] / (float)N1;
    float var = stats[128 + c] / (float)N1 - mean * mean;
    float sc = gamma[c] * rsqrtf(var + 1e-5f);
    params[c] = sc;
    params[128 + c] = beta[c] - mean * sc;
}

// ---- apply BN + relu, cast to bf16 ----
__global__ void k_hb(const float* __restrict__ h, const float* __restrict__ params,
                     __hip_bfloat16* __restrict__ hb) {
    int idx = blockIdx.x * blockDim.x + threadIdx.x;  // over N1*32 float4s
    if (idx >= N1 * 32) return;
    float4 v = ((const float4*)h)[idx];
    int cb = (idx & 31) * 4;
    float r0 = fmaxf(v.x * params[cb + 0] + params[128 + cb + 0], 0.f);
    float r1 = fmaxf(v.y * params[cb + 1] + params[128 + cb + 1], 0.f);
    float r2 = fmaxf(v.z * params[cb + 2] + params[128 + cb + 2], 0.f);
    float r3 = fmaxf(v.w * params[cb + 3] + params[128 + cb + 3], 0.f);
    union { __hip_bfloat16 b[4]; uint2 u; } o;
    o.b[0] = __float2bfloat16(r0); o.b[1] = __float2bfloat16(r1);
    o.b[2] = __float2bfloat16(r2); o.b[3] = __float2bfloat16(r3);
    *(uint2*)(hb + (size_t)idx * 4) = o.u;
}

// ---- pre-swizzle B fragments for MFMA: 5 matrices (W2[0..3], Wself2) ----
__global__ void k_bfrag(const float* __restrict__ W2, const float* __restrict__ Wself2,
                        __hip_bfloat16* __restrict__ BF) {
    int idx = blockIdx.x * blockDim.x + threadIdx.x;  // 5*16*64*8 = 40960
    if (idx >= 40960) return;
    int j = idx & 7, lane = (idx >> 3) & 63, sub = (idx >> 9) & 15, g = idx >> 13;
    int kt = sub >> 2, ct = sub & 3;
    int k = kt * 32 + (lane >> 4) * 8 + j;
    int col = ct * 16 + (lane & 15);
    float v = (g < 4) ? W2[(g * D + k) * DO + col] : Wself2[k * DO + col];
    BF[idx] = __float2bfloat16(v);
}

// ---- Z[g] = hb @ B[g], bf16 MFMA 16x16x32 ----
__global__ void __launch_bounds__(256) k_gemm(const __hip_bfloat16* __restrict__ hb,
                                              const __hip_bfloat16* __restrict__ BF,
                                              __hip_bfloat16* __restrict__ Z) {
    int g = blockIdx.y;
    int rows = (g == 4) ? N2 : N1;
    int row0 = blockIdx.x * 64;
    if (row0 >= rows) return;
    int wave = threadIdx.x >> 6, lane = threadIdx.x & 63;
    int r = row0 + wave * 16 + (lane & 15);
    int rl = (r < rows) ? r : 0;
    int kb = (lane >> 4) * 8;
    f32x4 acc[4] = {};
#pragma unroll
    for (int kt = 0; kt < 4; kt++) {
        bfrag8 a = *reinterpret_cast<const bfrag8*>(hb + (size_t)rl * D + kt * 32 + kb);
#pragma unroll
        for (int ct = 0; ct < 4; ct++) {
            bfrag8 b = *reinterpret_cast<const bfrag8*>(BF + ((((g * 4 + kt) * 4 + ct) * 64 + lane) * 8));
            acc[ct] = __builtin_amdgcn_mfma_f32_16x16x32_bf16(a, b, acc[ct], 0, 0, 0);
        }
    }
    int srow = row0 + wave * 16 + (lane >> 4) * 4;
    int col = lane & 15;
#pragma unroll
    for (int ct = 0; ct < 4; ct++) {
#pragma unroll
        for (int i = 0; i < 4; i++) {
            int rr = srow + i;
            if (rr < rows) Z[((size_t)g * N1 + rr) * DO + ct * 16 + col] = __float2bfloat16(acc[ct][i]);
        }
    }
}

// ---- out init: bias + self-loop term ----
__global__ void k_out_init(const float* __restrict__ b2, const __hip_bfloat16* __restrict__ Z,
                           float* __restrict__ out) {
    int idx = blockIdx.x * blockDim.x + threadIdx.x;
    if (idx >= N2 * DO) return;
    int o = idx & 63, d = idx >> 6;
    out[idx] = b2[o] + __bfloat162float(Z[((size_t)4 * N1 + d) * DO + o]);
}

// ---- edge scatter: out[dst] += Z[et][src] ----
__global__ void k_edges2(const int* __restrict__ src2, const int* __restrict__ dst2,
                         const int* __restrict__ et2, const __hip_bfloat16* __restrict__ Z,
                         float* __restrict__ out) {
    int gid = blockIdx.x * blockDim.x + threadIdx.x;
    int e = gid >> 6;
    int o = gid & 63;
    if (e >= E2) return;
    int s = src2[e], d = dst2[e], t = et2[e];
    float v = __bfloat162float(Z[((size_t)t * N1 + s) * DO + o]);
    atomicAdd(&out[d * DO + o], v);
}

// ---- in-place log-softmax over 64 cols ----
__global__ void k_lsm(float* __restrict__ out) {
    int d = blockIdx.x;
    int o = threadIdx.x;  // 64
    float v = out[d * DO + o];
    float m = v;
    for (int s = 32; s; s >>= 1) m = fmaxf(m, __shfl_xor(m, s, 64));
    float ex = expf(v - m);
    float sum = ex;
    for (int s = 32; s; s >>= 1) sum += __shfl_xor(sum, s, 64);
    out[d * DO + o] = v - m - logf(sum);
}

extern "C" void kernel_launch(void* const* d_in, const int* in_sizes, int n_in,
                              void* d_out, int out_size, void* d_ws, size_t ws_size,
                              hipStream_t stream) {
    const float* x      = (const float*)d_in[0];
    const int* src1     = (const int*)d_in[1];
    const int* dst1     = (const int*)d_in[2];
    const int* et1      = (const int*)d_in[3];
    const int* src2     = (const int*)d_in[4];
    const int* dst2     = (const int*)d_in[5];
    const int* et2      = (const int*)d_in[6];
    const int* hmap     = (const int*)d_in[7];
    const float* hist   = (const float*)d_in[8];
    const float* W1     = (const float*)d_in[9];
    const float* Wself1 = (const float*)d_in[10];
    const float* b1     = (const float*)d_in[11];
    const float* gamma  = (const float*)d_in[12];
    const float* beta   = (const float*)d_in[13];
    const float* W2     = (const float*)d_in[14];
    const float* Wself2 = (const float*)d_in[15];
    const float* b2     = (const float*)d_in[16];
    float* out = (float*)d_out;

    char* ws = (char*)d_ws;
    float* h            = (float*)(ws);                       // 30,720,000 B
    __hip_bfloat16* hb  = (__hip_bfloat16*)(ws + 30720000);   // 15,360,000 B
    __hip_bfloat16* Z   = (__hip_bfloat16*)(ws + 46080000);   // 38,400,000 B
    __hip_bfloat16* BF  = (__hip_bfloat16*)(ws + 84480000);   // 81,920 B
    float* stats        = (float*)(ws + 84561920);            // 1024 B (sum,sumsq)
    float* params       = stats + 256;                        // 1024 B (scale,shift)
    int* cnt            = (int*)(ws + 84566016);
    int* list           = cnt + 1;

    hipMemsetAsync(stats, 0, 1024, stream);
    hipMemsetAsync(cnt, 0, 4, stream);

    k_init_h<<<(N1 * 32 + 255) / 256, 256, 0, stream>>>(x, hmap, hist, Wself1, b1, h);
    k_scan<<<(E1 + 255) / 256, 256, 0, stream>>>(dst1, hmap, cnt, list);
    k_wl<<<256, 128, 0, stream>>>(x, src1, dst1, et1, W1, cnt, list, h);
    k_stats<<<1024, 256, 0, stream>>>(h, stats);
    k_params<<<1, 128, 0, stream>>>(stats, gamma, beta, params);
    k_hb<<<(N1 * 32 + 255) / 256, 256, 0, stream>>>(h, params, hb);
    k_bfrag<<<160, 256, 0, stream>>>(W2, Wself2, BF);
    dim3 gg((N1 + 63) / 64, 5);
    k_gemm<<<gg, 256, 0, stream>>>(hb, BF, Z);
    k_out_init<<<(N2 * DO + 255) / 256, 256, 0, stream>>>(b2, Z, out);
    k_edges2<<<E2 * 64 / 256, 256, 0, stream>>>(src2, dst2, et2, Z, out);
    k_lsm<<<N2, 64, 0, stream>>>(out);
}